// Round 11
// baseline (235.551 us; speedup 1.0000x reference)
//
#include <hip/hip_runtime.h>

#define DECAY 0.25f

typedef float fx4 __attribute__((ext_vector_type(4)));

__device__ __forceinline__ fx4 step4(fx4 mem, fx4 spk, fx4 xi, fx4* s_out)
{
    fx4 m = (mem - spk * 0.5f) * DECAY + xi;
    fx4 s;
    s.x = rintf(fminf(fmaxf(m.x, 0.f), 1.f));
    s.y = rintf(fminf(fmaxf(m.y, 0.f), 1.f));
    s.z = rintf(fminf(fmaxf(m.z, 0.f), 1.f));
    s.w = rintf(fminf(fmaxf(m.w, 0.f), 1.f));
    *s_out = s;
    return m;
}

__global__ __launch_bounds__(256) void lif_mem_update_kernel(
    const float* __restrict__ x, float* __restrict__ out, long long n4,
    unsigned rshift)
{
    // Bit-reverse the block index: blocks concurrently in flight sit at
    // maximally-spread plane offsets, decorrelating the 8 power-of-2-strided
    // streams across HBM channels/banks regardless of the address hash.
    unsigned c = __brev(blockIdx.x) >> rshift;
    long long i = (long long)c * blockDim.x + threadIdx.x;
    if (i >= n4) return;

    const fx4* __restrict__ x4 = (const fx4*)x;
    fx4* __restrict__ o4 = (fx4*)out;

    fx4 x0 = x4[i];
    fx4 x1 = x4[i + n4];
    fx4 x2 = x4[i + 2 * n4];
    fx4 x3 = x4[i + 3 * n4];

    fx4 zero = (fx4)(0.f);
    fx4 s0, s1, s2, s3;
    fx4 m;
    m = step4(zero, zero, x0, &s0);
    m = step4(m,    s0,   x1, &s1);
    m = step4(m,    s1,   x2, &s2);
    m = step4(m,    s2,   x3, &s3);

    o4[i]          = s0;
    o4[i + n4]     = s1;
    o4[i + 2 * n4] = s2;
    o4[i + 3 * n4] = s3;
}

extern "C" void kernel_launch(void* const* d_in, const int* in_sizes, int n_in,
                              void* d_out, int out_size, void* d_ws, size_t ws_size,
                              hipStream_t stream)
{
    const float* x = (const float*)d_in[0];
    float* out = (float*)d_out;

    long long total = (long long)in_sizes[0];   // 33554432 floats = [4][8388608]
    long long nplane = total / 4;               // 8388608 floats per plane
    long long n4 = nplane / 4;                  // 2097152 float4 per plane

    const int block = 256;
    long long grid = (n4 + block - 1) / block;  // 8192 = 2^13 blocks

    // bit-reversal width: log2(grid) (grid is a power of two here: 8192)
    unsigned bits = 0;
    while ((1LL << bits) < grid) ++bits;        // 13
    unsigned rshift = 32 - bits;

    lif_mem_update_kernel<<<(int)grid, block, 0, stream>>>(x, out, n4, rshift);
}